// Round 2
// baseline (3256.690 us; speedup 1.0000x reference)
//
#include <hip/hip_runtime.h>
#include <math.h>

static constexpr int TT = 512;   // sequence length
static constexpr int BB = 256;   // batch

// Barrier without vmcnt(0) drain: LDS-ordering only, so prefetch global loads
// stay in flight across it (T4/T14 pattern). "memory" clobbers fence compiler
// motion of LDS ops across the barrier.
#define BARRIER() do { \
    asm volatile("s_waitcnt lgkmcnt(0)" ::: "memory"); \
    __builtin_amdgcn_s_barrier(); \
    asm volatile("" ::: "memory"); \
  } while (0)

__device__ __forceinline__ float sigmoid_fast(float v) {
  // 1/(1+exp(-v)) = rcp(1 + exp2(-v*log2e)); v_exp_f32 + v_rcp_f32, ~1ulp each
  const float e = __builtin_amdgcn_exp2f(v * -1.44269504088896340736f);
  return __builtin_amdgcn_rcpf(1.0f + e);
}

// One workgroup per batch row; persistent over T with raw-barrier sync.
// Thread (s, c) owns column c of z and k-slice s of the fused dot
// z[c] = sum_k [x_t | h]_k * W[k][c], weights in registers.
template<int DIN, int H, int NS, bool HAS_X, bool WRITE_SEQ, bool WRITE_LAST, bool FUSE_DENSE>
__global__ void __launch_bounds__(4*H*NS, 1)
lstm_layer(const float* __restrict__ xin,    // [B,T,DIN] if HAS_X else [B,DIN]
           const float* __restrict__ Wk,     // [DIN,4H]
           const float* __restrict__ Wr,     // [H,4H]
           const float* __restrict__ bias,   // [4H]
           float* __restrict__ seq_out,      // [B,T,H]   (WRITE_SEQ)
           float* __restrict__ last_out,     // [B,H]     (WRITE_LAST)
           const float* __restrict__ Wout,   // [H,64]    (FUSE_DENSE)
           const float* __restrict__ boutp,  // [64]      (FUSE_DENSE)
           float* __restrict__ dense_out)    // [B,T,64]  (FUSE_DENSE)
{
  constexpr int C4H  = 4*H;
  constexpr int NTH  = C4H*NS;
  constexpr int KTOT = HAS_X ? (DIN + H) : H;
  constexpr int KS   = KTOT / NS;
  constexpr int XOFF = HAS_X ? DIN : 0;
  constexpr int XH   = XOFF + H;
  constexpr int NSTG = HAS_X ? (DIN/4) : 0;   // float4 stager threads

  const int tid = (int)threadIdx.x;
  const int b   = (int)blockIdx.x;
  const int s   = tid / C4H;                  // wave-uniform
  const int c   = tid % C4H;

  __shared__ __align__(16) float xh[2][XH];   // ping-pong [x_t | h_t]
  __shared__ __align__(16) float zp[NS*C4H];  // partial dots
  __shared__ __align__(16) float zl[HAS_X ? 4 : DIN];
  __shared__ __align__(16) float wout_s[FUSE_DENSE ? (H*64) : 4];
  __shared__ __align__(16) float hd[2][FUSE_DENSE ? H : 4];  // h copy for pipelined dense

  // ---- one-time: weight slice into registers (coalesced along c) ----
  float w[KS];
  #pragma unroll
  for (int i = 0; i < KS; ++i) {
    const int k = s*KS + i;
    const float* src;
    if (HAS_X) src = (k < DIN) ? (Wk + (size_t)k*C4H) : (Wr + (size_t)(k-DIN)*C4H);
    else       src = Wr + (size_t)k*C4H;
    w[i] = src[c];
  }

  float bi=0.f, bf=0.f, bg=0.f, bo=0.f, cst=0.f;
  if (tid < H) {
    bi = bias[tid]; bf = bias[H+tid]; bg = bias[2*H+tid]; bo = bias[3*H+tid];
  }

  // dense pipeline threads (dec2): waves 2-3, col pairs
  const bool is_dense = FUSE_DENSE && (tid >= H) && (tid < H + 128);
  const int  dcol  = is_dense ? ((tid - H) >> 1) : 0;
  const int  dhalf = is_dense ? ((tid - H) & 1)  : 0;
  float boutr = 0.f;
  if (is_dense) boutr = boutp[dcol];

  // stager threads: one float4 of the next input row each
  const bool is_stg = HAS_X && (tid >= C4H) && (tid < C4H + NSTG);
  const int  sx = tid - C4H;

  // ---- init LDS ----
  if (XOFF + tid < XH) xh[0][XOFF + tid] = 0.f;               // h0 = 0
  if constexpr (!HAS_X) { if (tid < DIN) zl[tid] = xin[(size_t)b*DIN + tid]; }
  if constexpr (FUSE_DENSE) {
    for (int i = tid; i < H*64/4; i += NTH)
      ((float4*)wout_s)[i] = ((const float4*)Wout)[i];
  }
  if constexpr (HAS_X) {
    if (is_stg) {
      const float4 v0 = *(const float4*)&xin[((size_t)b*TT)*DIN + 4*sx];
      *((float4*)&xh[0][0] + sx) = v0;
    }
  }
  BARRIER();

  // constant-input contribution (RepeatVector decoder layer 1)
  float zin = 0.f;
  if constexpr (!HAS_X) {
    if (s == 0) {
      #pragma unroll
      for (int k = 0; k < DIN; ++k) zin = fmaf(zl[k], Wk[(size_t)k*C4H + c], zin);
    }
  }

  auto do_dense = [&](int tpos) {  // out[b,tpos,:] = hd[tpos&1] @ Wout + bout
    const float* hp = &hd[tpos & 1][dhalf*64];
    const float* wp = &wout_s[(size_t)(dhalf*64)*64 + dcol];
    float a0 = 0.f, a1 = 0.f;
    #pragma unroll
    for (int j = 0; j < 64; j += 2) {
      a0 = fmaf(hp[j],   wp[(size_t)j*64],     a0);
      a1 = fmaf(hp[j+1], wp[(size_t)(j+1)*64], a1);
    }
    float a = a0 + a1;
    a += __shfl_xor(a, 1);
    if (dhalf == 0)
      dense_out[((size_t)b*TT + tpos)*64 + dcol] = a + boutr;
  };

  for (int t = 0; t < TT; ++t) {
    const int cur = t & 1, nxt = cur ^ 1;

    // issue next-row prefetch FIRST (drained only at its LDS-write use in
    // phase B; covered by phase-A compute since barriers skip vmcnt)
    float4 xr;
    if (is_stg && (t+1) < TT)
      xr = *(const float4*)&xin[((size_t)b*TT + (t+1))*DIN + 4*sx];

    // ---- phase A: fused input+recurrent dot ----
    {
      const float4* xv = (const float4*)&xh[cur][s*KS];
      float a0 = zin, a1 = 0.f, a2 = 0.f, a3 = 0.f;
      #pragma unroll
      for (int j = 0; j < KS/4; ++j) {
        const float4 v = xv[j];
        a0 = fmaf(v.x, w[4*j],   a0);
        a1 = fmaf(v.y, w[4*j+1], a1);
        a2 = fmaf(v.z, w[4*j+2], a2);
        a3 = fmaf(v.w, w[4*j+3], a3);
      }
      zp[s*C4H + c] = (a0 + a1) + (a2 + a3);
    }
    BARRIER();

    // ---- phase B: gates (waves 0-1) | pipelined dense (waves 2-3) | stage x (stagers) ----
    if (tid < H) {
      float vi=bi, vf=bf, vg=bg, vo=bo;
      #pragma unroll
      for (int ss = 0; ss < NS; ++ss) {
        vi += zp[ss*C4H + tid];
        vf += zp[ss*C4H + H   + tid];
        vg += zp[ss*C4H + 2*H + tid];
        vo += zp[ss*C4H + 3*H + tid];
      }
      const float gi = sigmoid_fast(vi);
      const float gf = sigmoid_fast(vf);
      const float go = sigmoid_fast(vo);
      const float gg = fmaxf(vg, 0.f);          // activation = relu
      cst = fmaf(gf, cst, gi*gg);               // c = f*c + i*g
      const float h = go * fmaxf(cst, 0.f);     // h = o * relu(c)
      xh[nxt][XOFF + tid] = h;
      if constexpr (FUSE_DENSE) hd[t & 1][tid] = h;
      if constexpr (WRITE_SEQ)  seq_out[((size_t)b*TT + t)*H + tid] = h;
      if constexpr (WRITE_LAST) { if (t == TT-1) last_out[(size_t)b*H + tid] = h; }
    }
    if (is_stg && (t+1) < TT)
      *((float4*)&xh[nxt][0] + sx) = xr;        // implicit vmcnt wait, stager waves only
    if constexpr (FUSE_DENSE) {
      if (is_dense && t >= 1) do_dense(t - 1);
    }
    BARRIER();
  }

  if constexpr (FUSE_DENSE) {                   // drain the 1-step dense pipeline
    if (is_dense) do_dense(TT - 1);
  }
}

extern "C" void kernel_launch(void* const* d_in, const int* in_sizes, int n_in,
                              void* d_out, int out_size, void* d_ws, size_t ws_size,
                              hipStream_t stream) {
  const float* x    = (const float*)d_in[0];
  const float* Wk1  = (const float*)d_in[1];
  const float* Wr1  = (const float*)d_in[2];
  const float* b1   = (const float*)d_in[3];
  const float* Wk2  = (const float*)d_in[4];
  const float* Wr2  = (const float*)d_in[5];
  const float* b2   = (const float*)d_in[6];
  const float* Wd1k = (const float*)d_in[7];
  const float* Wd1r = (const float*)d_in[8];
  const float* bd1  = (const float*)d_in[9];
  const float* Wd2k = (const float*)d_in[10];
  const float* Wd2r = (const float*)d_in[11];
  const float* bd2  = (const float*)d_in[12];
  const float* Wout = (const float*)d_in[13];
  const float* bout = (const float*)d_in[14];
  float* out = (float*)d_out;

  const size_t h1_elems = (size_t)BB * TT * 128;
  const size_t need = (h1_elems + (size_t)BB*64) * sizeof(float);
  if (ws_size < need) return;
  float* h1 = (float*)d_ws;
  float* z  = h1 + h1_elems;
  float* d1 = h1;  // h1 dead after enc2

  // encoder layer 1: 64 -> 128, return sequences
  lstm_layer<64,128,2,true, true, false,false><<<BB,1024,0,stream>>>(x,  Wk1,  Wr1,  b1,  h1, nullptr, nullptr, nullptr, nullptr);
  // encoder layer 2: 128 -> 64, return last state
  lstm_layer<128,64,4,true, false,true, false><<<BB,1024,0,stream>>>(h1, Wk2,  Wr2,  b2,  nullptr, z, nullptr, nullptr, nullptr);
  // decoder layer 1: constant input z (RepeatVector), 64 -> 64
  lstm_layer<64, 64,4,false,true, false,false><<<BB,1024,0,stream>>>(z,  Wd1k, Wd1r, bd1, d1, nullptr, nullptr, nullptr, nullptr);
  // decoder layer 2: 64 -> 128, fused TimeDistributed Dense 128 -> 64
  lstm_layer<64,128,2,true, false,false,true ><<<BB,1024,0,stream>>>(d1, Wd2k, Wd2r, bd2, nullptr, nullptr, Wout, bout, out);
}

// Round 3
// 2517.466 us; speedup vs baseline: 1.2936x; 1.2936x over previous
//
#include <hip/hip_runtime.h>

static constexpr int TT = 512;   // sequence length
static constexpr int BB = 256;   // batch

// LDS-only barrier: no vmcnt(0) drain, so global loads/stores stay in flight
// across it (T4/T14 pattern). lgkmcnt(0) makes prior LDS writes visible.
#define BARRIER() do { \
    asm volatile("s_waitcnt lgkmcnt(0)" ::: "memory"); \
    __builtin_amdgcn_s_barrier(); \
    asm volatile("" ::: "memory"); \
  } while (0)

__device__ __forceinline__ float sigmoid_fast(float v) {
  // 1/(1+2^(-v*log2e)); v_exp_f32 + v_rcp_f32 (validated: absmax 3.8e-6 in r2)
  const float e = __builtin_amdgcn_exp2f(v * -1.44269504088896340736f);
  return __builtin_amdgcn_rcpf(1.0f + e);
}

// One workgroup per batch row, persistent over T, ONE barrier per step.
// Thread (u, sl): u = unit, sl = k-slice; computes all 4 gate partial dots
// for unit u over k-slice sl with weights in registers; slices of a unit are
// adjacent lanes -> shfl_xor butterfly reduction; every lane then computes
// the gates redundantly; sl==0 lane writes h to the ping-pong LDS buffer.
// CONST_X: input row is constant over t (RepeatVector) - staged once.
// FUSE_DENSE: TimeDistributed Dense pipelined 2 steps behind the recurrence,
// spread over all waves (wave w owns k in [8w,8w+8)), dp double-buffered.
template<int DIN, int H, int NSu, bool CONST_X, bool WRITE_SEQ, bool WRITE_LAST, bool FUSE_DENSE>
__global__ void __launch_bounds__(H*NSu, 4)
lstm_unit(const float* __restrict__ xin,    // [B,T,DIN] or [B,DIN] if CONST_X
          const float* __restrict__ Wk,     // [DIN,4H]
          const float* __restrict__ Wr,     // [H,4H]
          const float* __restrict__ bias,   // [4H]
          float* __restrict__ seq_out,      // [B,T,H]  (WRITE_SEQ)
          float* __restrict__ last_out,     // [B,H]    (WRITE_LAST)
          const float* __restrict__ Wout,   // [H,64]   (FUSE_DENSE)
          const float* __restrict__ boutp,  // [64]     (FUSE_DENSE)
          float* __restrict__ dense_out)    // [B,T,64] (FUSE_DENSE)
{
  constexpr int NTH  = H * NSu;
  constexpr int KTOT = DIN + H;
  constexpr int SL   = KTOT / NSu;          // k's per slice
  constexpr int C4H  = 4 * H;
  constexpr int XH   = DIN + H;             // [x | h]
  constexpr int NW   = NTH / 64;            // waves
  static_assert(SL * NSu == KTOT && (SL % 4) == 0, "slice must be float4-able");
  static_assert((NSu & (NSu - 1)) == 0 && NSu <= 64, "NSu pow2");

  const int tid = (int)threadIdx.x;
  const int b   = (int)blockIdx.x;
  const int l   = tid & 63;
  const int wv  = tid >> 6;
  const int sl  = l & (NSu - 1);            // k-slice (low lane bits)
  const int u   = wv * (64 / NSu) + (l / NSu);

  __shared__ __align__(16) float xh[2][XH];                      // ping-pong [x_t | h_t]
  __shared__ __align__(16) float wout_s[FUSE_DENSE ? H * 64 : 4];
  __shared__ __align__(16) float dp[2][FUSE_DENSE ? NW * 64 : 4];

  // ---- one-time: per-thread weights (4 gates x SL k's) into registers ----
  float w[SL * 4];
  #pragma unroll
  for (int i = 0; i < SL; ++i) {
    const int k = sl * SL + i;
    const float* col = (k < DIN) ? &Wk[(size_t)k * C4H] : &Wr[(size_t)(k - DIN) * C4H];
    #pragma unroll
    for (int g = 0; g < 4; ++g) w[i * 4 + g] = col[g * H + u];
  }
  const float bi_ = bias[u], bf_ = bias[H + u], bg_ = bias[2 * H + u], bo_ = bias[3 * H + u];
  float boutr = 0.f;
  if (FUSE_DENSE && wv == NW - 1) boutr = boutp[l];

  // ---- prologue: h0 = 0, stage x_0 (both buffers if constant) ----
  if (tid < H) xh[0][DIN + tid] = 0.f;
  if (tid < DIN / 4) {
    const float4 v = *(const float4*)&xin[(CONST_X ? (size_t)b * DIN
                                                   : (size_t)b * TT * DIN) + 4 * tid];
    *((float4*)&xh[0][0] + tid) = v;
    if (CONST_X) *((float4*)&xh[1][0] + tid) = v;
  }
  if (FUSE_DENSE) {
    for (int i = tid; i < H * 64 / 4; i += NTH)
      ((float4*)wout_s)[i] = ((const float4*)Wout)[i];
  }
  BARRIER();

  float cst = 0.f;
  constexpr int TEND = FUSE_DENSE ? TT + 2 : TT;

  for (int t = 0; t < TEND; ++t) {
    const int cur = t & 1, nxt = cur ^ 1;

    // issue next-row prefetch FIRST; consumed at the LDS write below
    // (HBM latency hidden under this step's FMAs; barrier doesn't drain vmcnt)
    float4 xr;
    const bool do_stage = (!CONST_X) && (tid < DIN / 4) && (t + 1 < TT);
    if (do_stage) xr = *(const float4*)&xin[((size_t)b * TT + (t + 1)) * DIN + 4 * tid];

    if (t < TT) {
      // ---- fused input+recurrent 4-gate dot over this thread's k-slice ----
      const float4* xv = (const float4*)&xh[cur][sl * SL];
      float ai = 0.f, af = 0.f, ag = 0.f, ao = 0.f;
      #pragma unroll
      for (int j = 0; j < SL / 4; ++j) {
        const float4 v = xv[j];
        ai = fmaf(v.x, w[(4*j+0)*4+0], ai); af = fmaf(v.x, w[(4*j+0)*4+1], af);
        ag = fmaf(v.x, w[(4*j+0)*4+2], ag); ao = fmaf(v.x, w[(4*j+0)*4+3], ao);
        ai = fmaf(v.y, w[(4*j+1)*4+0], ai); af = fmaf(v.y, w[(4*j+1)*4+1], af);
        ag = fmaf(v.y, w[(4*j+1)*4+2], ag); ao = fmaf(v.y, w[(4*j+1)*4+3], ao);
        ai = fmaf(v.z, w[(4*j+2)*4+0], ai); af = fmaf(v.z, w[(4*j+2)*4+1], af);
        ag = fmaf(v.z, w[(4*j+2)*4+2], ag); ao = fmaf(v.z, w[(4*j+2)*4+3], ao);
        ai = fmaf(v.w, w[(4*j+3)*4+0], ai); af = fmaf(v.w, w[(4*j+3)*4+1], af);
        ag = fmaf(v.w, w[(4*j+3)*4+2], ag); ao = fmaf(v.w, w[(4*j+3)*4+3], ao);
      }
      // ---- in-wave butterfly reduction across the NSu slices of unit u ----
      #pragma unroll
      for (int m = 1; m < NSu; m <<= 1) {
        ai += __shfl_xor(ai, m); af += __shfl_xor(af, m);
        ag += __shfl_xor(ag, m); ao += __shfl_xor(ao, m);
      }
      // ---- gates (all lanes, redundant -> no divergence) ----
      const float gi = sigmoid_fast(ai + bi_);
      const float gf = sigmoid_fast(af + bf_);
      const float go = sigmoid_fast(ao + bo_);
      const float gg = fmaxf(ag + bg_, 0.f);       // activation = relu
      cst = fmaf(gf, cst, gi * gg);                // c = f*c + i*g
      const float h = go * fmaxf(cst, 0.f);        // h = o * relu(c)
      if (sl == 0) {
        xh[nxt][DIN + u] = h;
        if (WRITE_SEQ) seq_out[((size_t)b * TT + t) * H + u] = h;
        if (WRITE_LAST) { if (t == TT - 1) last_out[(size_t)b * H + u] = h; }
      }
    }
    if (do_stage) *((float4*)&xh[nxt][0] + tid) = xr;

    if (FUSE_DENSE) {
      // ---- dense partial of h(t-1) (sits in xh[cur]): wave wv owns 8 k's ----
      if (t >= 1 && t <= TT) {
        const float4 h0 = *(const float4*)&xh[cur][DIN + 8 * wv];
        const float4 h1 = *(const float4*)&xh[cur][DIN + 8 * wv + 4];
        float a = 0.f;
        a = fmaf(h0.x, wout_s[(8*wv+0)*64 + l], a);
        a = fmaf(h0.y, wout_s[(8*wv+1)*64 + l], a);
        a = fmaf(h0.z, wout_s[(8*wv+2)*64 + l], a);
        a = fmaf(h0.w, wout_s[(8*wv+3)*64 + l], a);
        a = fmaf(h1.x, wout_s[(8*wv+4)*64 + l], a);
        a = fmaf(h1.y, wout_s[(8*wv+5)*64 + l], a);
        a = fmaf(h1.z, wout_s[(8*wv+6)*64 + l], a);
        a = fmaf(h1.w, wout_s[(8*wv+7)*64 + l], a);
        dp[(t - 1) & 1][wv * 64 + l] = a;
      }
      // ---- dense reduce of step t-2 (dp written at t-1, sealed by barrier) ----
      if (t >= 2 && wv == NW - 1) {
        float o = boutr;
        #pragma unroll
        for (int j = 0; j < NW; ++j) o += dp[t & 1][j * 64 + l];
        dense_out[((size_t)b * TT + (t - 2)) * 64 + l] = o;
      }
    }
    if (t < TEND - 1) BARRIER();
  }
}

extern "C" void kernel_launch(void* const* d_in, const int* in_sizes, int n_in,
                              void* d_out, int out_size, void* d_ws, size_t ws_size,
                              hipStream_t stream) {
  const float* x    = (const float*)d_in[0];
  const float* Wk1  = (const float*)d_in[1];
  const float* Wr1  = (const float*)d_in[2];
  const float* b1   = (const float*)d_in[3];
  const float* Wk2  = (const float*)d_in[4];
  const float* Wr2  = (const float*)d_in[5];
  const float* b2   = (const float*)d_in[6];
  const float* Wd1k = (const float*)d_in[7];
  const float* Wd1r = (const float*)d_in[8];
  const float* bd1  = (const float*)d_in[9];
  const float* Wd2k = (const float*)d_in[10];
  const float* Wd2r = (const float*)d_in[11];
  const float* bd2  = (const float*)d_in[12];
  const float* Wout = (const float*)d_in[13];
  const float* bout = (const float*)d_in[14];
  float* out = (float*)d_out;

  // ws: h1 [B,T,128] (64MB; d1 [B,T,64] overlays it after enc2), z [B,64]
  const size_t h1_elems = (size_t)BB * TT * 128;
  const size_t need = (h1_elems + (size_t)BB * 64) * sizeof(float);
  if (ws_size < need) return;
  float* h1 = (float*)d_ws;
  float* z  = h1 + h1_elems;
  float* d1 = h1;  // h1 dead after enc2

  // encoder 1: 64 -> 128, seq out          (NSu=8,  SL=24, w[96])
  lstm_unit<64, 128, 8,  false, true,  false, false><<<BB, 1024, 0, stream>>>(
      x,  Wk1,  Wr1,  b1,  h1,      nullptr, nullptr, nullptr, nullptr);
  // encoder 2: 128 -> 64, last state only  (NSu=16, SL=12, w[48])
  lstm_unit<128, 64, 16, false, false, true,  false><<<BB, 1024, 0, stream>>>(
      h1, Wk2,  Wr2,  b2,  nullptr, z,       nullptr, nullptr, nullptr);
  // decoder 1: const z (RepeatVector) -> 64, seq out (NSu=16, SL=8, w[32])
  lstm_unit<64,  64, 16, true,  true,  false, false><<<BB, 1024, 0, stream>>>(
      z,  Wd1k, Wd1r, bd1, d1,      nullptr, nullptr, nullptr, nullptr);
  // decoder 2: 64 -> 128 + fused TimeDistributed Dense 128 -> 64 (NSu=8, SL=24)
  lstm_unit<64, 128, 8,  false, false, false, true ><<<BB, 1024, 0, stream>>>(
      d1, Wd2k, Wd2r, bd2, nullptr, nullptr, Wout,   bout,    out);
}

// Round 4
// 1422.105 us; speedup vs baseline: 2.2900x; 1.7702x over previous
//
#include <hip/hip_runtime.h>

static constexpr int TT = 512;   // sequence length
static constexpr int BB = 256;   // batch

// LDS-only barrier: no vmcnt(0) drain, so global loads stay in flight across
// it (T4/T14 pattern). lgkmcnt(0) makes prior LDS writes visible.
#define BARRIER() do { \
    asm volatile("s_waitcnt lgkmcnt(0)" ::: "memory"); \
    __builtin_amdgcn_s_barrier(); \
    asm volatile("" ::: "memory"); \
  } while (0)

__device__ __forceinline__ float sigmoid_fast(float v) {
  // 1/(1+2^(-v*log2e)); v_exp_f32 + v_rcp_f32 (validated: absmax 3.8e-6)
  const float e = __builtin_amdgcn_exp2f(v * -1.44269504088896340736f);
  return __builtin_amdgcn_rcpf(1.0f + e);
}

// Butterfly add over lane bit 0/1 via DPP quad_perm (VALU, keeps DS pipe free)
__device__ __forceinline__ float dpp_add_xor1(float v) {
  const int p = __builtin_amdgcn_update_dpp(0, __builtin_bit_cast(int, v),
                                            0xB1 /*[1,0,3,2]*/, 0xF, 0xF, true);
  return v + __builtin_bit_cast(float, p);
}
__device__ __forceinline__ float dpp_add_xor2(float v) {
  const int p = __builtin_amdgcn_update_dpp(0, __builtin_bit_cast(int, v),
                                            0x4E /*[2,3,0,1]*/, 0xF, 0xF, true);
  return v + __builtin_bit_cast(float, p);
}
__device__ __forceinline__ float swz_add_xor4(float v) {
  const int p = __builtin_amdgcn_ds_swizzle(__builtin_bit_cast(int, v), 0x101F);
  return v + __builtin_bit_cast(float, p);
}

// One workgroup (512 thr = 8 waves, 2/SIMD -> 256-reg budget) per batch row,
// persistent over T, ONE barrier per step. Thread (u, sl): computes all 4
// gate partial dots for unit u over k-slice sl, weights in arch VGPRs;
// slices adjacent lanes -> DPP/swizzle butterfly; gates redundant per lane.
// CONST_X: RepeatVector input staged once into both ping-pong buffers.
// FUSE_DENSE: TimeDistributed Dense, wave wv owns k's [16wv,16wv+16) with
// wout in registers, h read wave-uniform; dp double-buffered, 2-step pipe.
template<int DIN, int H, int NSu, bool CONST_X, bool WRITE_SEQ, bool WRITE_LAST, bool FUSE_DENSE>
__global__ void __launch_bounds__(512, 2)
lstm_unit(const float* __restrict__ xin,    // [B,T,DIN] or [B,DIN] if CONST_X
          const float* __restrict__ Wk,     // [DIN,4H]
          const float* __restrict__ Wr,     // [H,4H]
          const float* __restrict__ bias,   // [4H]
          float* __restrict__ seq_out,      // [B,T,H]  (WRITE_SEQ)
          float* __restrict__ last_out,    // [B,H]    (WRITE_LAST)
          const float* __restrict__ Wout,   // [H,64]   (FUSE_DENSE)
          const float* __restrict__ boutp,  // [64]     (FUSE_DENSE)
          float* __restrict__ dense_out)    // [B,T,64] (FUSE_DENSE)
{
  constexpr int NTH  = 512;
  static_assert(H * NSu == NTH, "block = H*NSu = 512");
  constexpr int KTOT = DIN + H;
  constexpr int SL   = KTOT / NSu;          // k's per slice
  constexpr int C4H  = 4 * H;
  constexpr int XH   = DIN + H;
  constexpr int NW   = NTH / 64;            // 8 waves
  constexpr int UPW  = 64 / NSu;            // units per wave
  constexpr int DK   = FUSE_DENSE ? (H / NW) : 4;   // dense k's per wave (16)
  static_assert(SL * NSu == KTOT && (SL % 4) == 0, "slice float4-able");
  static_assert(NSu == 4 || NSu == 8, "butterfly depth");

  const int tid = (int)threadIdx.x;
  const int b   = (int)blockIdx.x;
  const int l   = tid & 63;
  const int wv  = tid >> 6;
  const int sl  = l & (NSu - 1);
  const int u   = wv * UPW + (l / NSu);

  __shared__ __align__(16) float xh0[XH], xh1[XH];   // ping-pong [x_t | h_t]
  __shared__ __align__(16) float dp[2][FUSE_DENSE ? NW * 64 : 4];

  // ---- one-time: per-thread weights (4 gates x SL k's) into registers ----
  float w[SL * 4];
  #pragma unroll
  for (int i = 0; i < SL; ++i) {
    const int k = sl * SL + i;
    const float* col = (k < DIN) ? &Wk[(size_t)k * C4H] : &Wr[(size_t)(k - DIN) * C4H];
    #pragma unroll
    for (int g = 0; g < 4; ++g) w[i * 4 + g] = col[g * H + u];
  }
  const float bi_ = bias[u], bf_ = bias[H + u], bg_ = bias[2 * H + u], bo_ = bias[3 * H + u];

  float wout_r[DK];
  float boutr = 0.f;
  if constexpr (FUSE_DENSE) {
    #pragma unroll
    for (int j = 0; j < DK; ++j) wout_r[j] = Wout[(size_t)(DK * wv + j) * 64 + l];
    boutr = boutp[l];
  }

  // ---- prologue: h0 = 0, stage x_0 (both buffers if constant) ----
  if (tid < H) xh0[DIN + tid] = 0.f;
  if (tid < DIN / 4) {
    const float4 v = *(const float4*)&xin[(CONST_X ? (size_t)b * DIN
                                                   : (size_t)b * TT * DIN) + 4 * tid];
    *((float4*)xh0 + tid) = v;
    if (CONST_X) *((float4*)xh1 + tid) = v;
  }
  BARRIER();

  float cst = 0.f;
  constexpr int TEND = FUSE_DENSE ? TT + 2 : TT;

  for (int t = 0; t < TEND; ++t) {
    float* xc = (t & 1) ? xh1 : xh0;   // holds x_t and h_{t-1}
    float* xn = (t & 1) ? xh0 : xh1;

    // issue next-row prefetch FIRST; vmcnt-waited only at its LDS write
    float4 xr;
    const bool do_stage = (!CONST_X) && (tid < DIN / 4) && (t + 1 < TT);
    if (do_stage) xr = *(const float4*)&xin[((size_t)b * TT + (t + 1)) * DIN + 4 * tid];

    if (t < TT) {
      // ---- fused input+recurrent 4-gate dot over this thread's k-slice ----
      const float4* xv = (const float4*)(xc + sl * SL);
      float ai = 0.f, af = 0.f, ag = 0.f, ao = 0.f;
      #pragma unroll
      for (int j = 0; j < SL / 4; ++j) {
        const float4 v = xv[j];
        const float* wj = &w[16 * j];
        ai = fmaf(v.x, wj[0],  ai);  af = fmaf(v.x, wj[1],  af);
        ag = fmaf(v.x, wj[2],  ag);  ao = fmaf(v.x, wj[3],  ao);
        ai = fmaf(v.y, wj[4],  ai);  af = fmaf(v.y, wj[5],  af);
        ag = fmaf(v.y, wj[6],  ag);  ao = fmaf(v.y, wj[7],  ao);
        ai = fmaf(v.z, wj[8],  ai);  af = fmaf(v.z, wj[9],  af);
        ag = fmaf(v.z, wj[10], ag);  ao = fmaf(v.z, wj[11], ao);
        ai = fmaf(v.w, wj[12], ai);  af = fmaf(v.w, wj[13], af);
        ag = fmaf(v.w, wj[14], ag);  ao = fmaf(v.w, wj[15], ao);
      }
      // ---- butterfly across NSu slices: DPP (VALU) + swizzle for bit 2 ----
      ai = dpp_add_xor1(ai); af = dpp_add_xor1(af);
      ag = dpp_add_xor1(ag); ao = dpp_add_xor1(ao);
      ai = dpp_add_xor2(ai); af = dpp_add_xor2(af);
      ag = dpp_add_xor2(ag); ao = dpp_add_xor2(ao);
      if constexpr (NSu == 8) {
        ai = swz_add_xor4(ai); af = swz_add_xor4(af);
        ag = swz_add_xor4(ag); ao = swz_add_xor4(ao);
      }
      // ---- gates (all lanes, redundant -> no divergence) ----
      const float gi = sigmoid_fast(ai + bi_);
      const float gf = sigmoid_fast(af + bf_);
      const float go = sigmoid_fast(ao + bo_);
      const float gg = fmaxf(ag + bg_, 0.f);       // activation = relu
      cst = fmaf(gf, cst, gi * gg);                // c = f*c + i*g
      const float h = go * fmaxf(cst, 0.f);        // h = o * relu(c)
      if (sl == 0) {
        xn[DIN + u] = h;
        if constexpr (WRITE_SEQ)  seq_out[((size_t)b * TT + t) * H + u] = h;
        if constexpr (WRITE_LAST) { if (t == TT - 1) last_out[(size_t)b * H + u] = h; }
      }
    }
    if (do_stage) *((float4*)xn + tid) = xr;

    if constexpr (FUSE_DENSE) {
      // ---- dense partial of h(t-1) (in xc): wave-uniform h reads, reg wout ----
      if (t >= 1 && t <= TT) {
        const float* hsrc = xc + DIN + DK * wv;
        float a = 0.f;
        #pragma unroll
        for (int j = 0; j < DK; j += 4) {
          const float4 hv = *(const float4*)(hsrc + j);
          a = fmaf(hv.x, wout_r[j + 0], a);
          a = fmaf(hv.y, wout_r[j + 1], a);
          a = fmaf(hv.z, wout_r[j + 2], a);
          a = fmaf(hv.w, wout_r[j + 3], a);
        }
        dp[(t - 1) & 1][wv * 64 + l] = a;
      }
      // ---- reduce step t-2 (dp sealed by the t-1 barrier), wave NW-1 ----
      if (t >= 2 && wv == NW - 1) {
        const float* dq = dp[t & 1];
        float o = boutr;
        #pragma unroll
        for (int j = 0; j < NW; ++j) o += dq[j * 64 + l];
        dense_out[((size_t)b * TT + (t - 2)) * 64 + l] = o;
      }
    }
    if (t < TEND - 1) BARRIER();
  }
}

extern "C" void kernel_launch(void* const* d_in, const int* in_sizes, int n_in,
                              void* d_out, int out_size, void* d_ws, size_t ws_size,
                              hipStream_t stream) {
  const float* x    = (const float*)d_in[0];
  const float* Wk1  = (const float*)d_in[1];
  const float* Wr1  = (const float*)d_in[2];
  const float* b1   = (const float*)d_in[3];
  const float* Wk2  = (const float*)d_in[4];
  const float* Wr2  = (const float*)d_in[5];
  const float* b2   = (const float*)d_in[6];
  const float* Wd1k = (const float*)d_in[7];
  const float* Wd1r = (const float*)d_in[8];
  const float* bd1  = (const float*)d_in[9];
  const float* Wd2k = (const float*)d_in[10];
  const float* Wd2r = (const float*)d_in[11];
  const float* bd2  = (const float*)d_in[12];
  const float* Wout = (const float*)d_in[13];
  const float* bout = (const float*)d_in[14];
  float* out = (float*)d_out;

  // ws: h1 [B,T,128] (64MB; d1 [B,T,64] overlays it after enc2), z [B,64]
  const size_t h1_elems = (size_t)BB * TT * 128;
  const size_t need = (h1_elems + (size_t)BB * 64) * sizeof(float);
  if (ws_size < need) return;
  float* h1 = (float*)d_ws;
  float* z  = h1 + h1_elems;
  float* d1 = h1;  // h1 dead after enc2

  // encoder 1: 64 -> 128, seq out           (NSu=4, SL=48, w[192])
  lstm_unit<64, 128, 4, false, true,  false, false><<<BB, 512, 0, stream>>>(
      x,  Wk1,  Wr1,  b1,  h1,      nullptr, nullptr, nullptr, nullptr);
  // encoder 2: 128 -> 64, last state only   (NSu=8, SL=24, w[96])
  lstm_unit<128, 64, 8, false, false, true,  false><<<BB, 512, 0, stream>>>(
      h1, Wk2,  Wr2,  b2,  nullptr, z,       nullptr, nullptr, nullptr);
  // decoder 1: const z (RepeatVector) -> 64 (NSu=8, SL=16, w[64])
  lstm_unit<64,  64, 8, true,  true,  false, false><<<BB, 512, 0, stream>>>(
      z,  Wd1k, Wd1r, bd1, d1,      nullptr, nullptr, nullptr, nullptr);
  // decoder 2: 64 -> 128 + fused Dense 128->64 (NSu=4, SL=48, w[192]+wout[16])
  lstm_unit<64, 128, 4, false, false, false, true ><<<BB, 512, 0, stream>>>(
      d1, Wd2k, Wd2r, bd2, nullptr, nullptr, Wout,   bout,    out);
}